// Round 10
// baseline (448.845 us; speedup 1.0000x reference)
//
#include <hip/hip_runtime.h>
#include <hip/hip_bf16.h>

typedef __attribute__((ext_vector_type(8))) unsigned short ushort8;
typedef __attribute__((ext_vector_type(8))) short bf16x8;
typedef __attribute__((ext_vector_type(4))) float f32x4;
typedef __attribute__((ext_vector_type(2))) float f32x2;

#define TM 32      // motion frames
#define NB 256     // batch
#define NC 512     // channels in
#define NO 512     // channels out
#define HW 16      // H*W
#define TXT 256

#define SB()     __builtin_amdgcn_sched_barrier(0)
#define BAR()    __builtin_amdgcn_s_barrier()
#define WAITV4() asm volatile("s_waitcnt vmcnt(4) lgkmcnt(0)" ::: "memory")
#define WAITV2() asm volatile("s_waitcnt vmcnt(2) lgkmcnt(0)" ::: "memory")
#define WAITV0() asm volatile("s_waitcnt vmcnt(0) lgkmcnt(0)" ::: "memory")
#define WAITL()  asm volatile("s_waitcnt lgkmcnt(0)" ::: "memory")

__device__ __forceinline__ float bf2f(unsigned short u) {
    return __uint_as_float(((unsigned)u) << 16);
}
__device__ __forceinline__ unsigned pk2bf(float lo, float hi) {
    __hip_bfloat162 h = __float22bfloat162_rn(float2{lo, hi});
    return *reinterpret_cast<unsigned*>(&h);
}
__device__ __forceinline__ float leaky_f(float x) { return fmaxf(x, 0.2f * x); }

// packed-FP32 VOP3P (gfx90a+/gfx950); no v_pk_max_f32 on CDNA -> max stays scalar
__device__ __forceinline__ f32x2 pk_fma2(f32x2 a, f32x2 b, f32x2 c) {
    f32x2 d;
    asm("v_pk_fma_f32 %0, %1, %2, %3" : "=v"(d) : "v"(a), "v"(b), "v"(c));
    return d;
}
__device__ __forceinline__ f32x2 pk_mul2(f32x2 a, f32x2 b) {
    f32x2 d;
    asm("v_pk_mul_f32 %0, %1, %2" : "=v"(d) : "v"(a), "v"(b));
    return d;
}

__device__ __forceinline__ void gl_lds16(const void* g, void* l) {
    __builtin_amdgcn_global_load_lds(
        (const __attribute__((address_space(1))) unsigned int*)g,
        (__attribute__((address_space(3))) unsigned int*)l, 16, 0, 0);
}

// ---------------- K0a: weights -> bf16 (+ Wp2 transpose) ---------------------------------
__global__ __launch_bounds__(256)
void kprep_w(const float* __restrict__ Wmm, const float* __restrict__ Wp1,
             const float* __restrict__ Wp2,
             unsigned short* __restrict__ WmmBf, unsigned short* __restrict__ Wp1Bf,
             float* __restrict__ Wp2T)
{
    const int bid = blockIdx.x, tid = threadIdx.x;
    if (bid < 512) {
        const float2 v = *reinterpret_cast<const float2*>(Wmm + (size_t)bid * 512 + tid * 2);
        ((unsigned*)WmmBf)[bid * 256 + tid] = pk2bf(v.x, v.y);
    } else if (bid < 1024) {
        const int o = bid - 512;
        const float2 v = *reinterpret_cast<const float2*>(Wp1 + (size_t)o * 768 + tid * 2);
        ((unsigned*)Wp1Bf)[o * 256 + tid] = pk2bf(v.x, v.y);
    } else {
        const int i = (bid - 1024) * 256 + tid;   // 0..8191
        const int hw = i >> 9, o = i & 511;
        Wp2T[i] = Wp2[o * 16 + hw];
    }
}

// ---------------- K0b: motion diff (8 t per block), LDS transpose, coalesced R/W ---------
__global__ __launch_bounds__(256)
void kprep_diff(const float* __restrict__ frames, unsigned short* __restrict__ mdT)
{
    __shared__ __attribute__((aligned(16))) char lds[16 * 1040];
    const int bx = blockIdx.x;
    const int tg = bx >> 8, b = bx & 255;       // tg 0..3 -> t = tg*8 .. +7
    const int t0 = tg * 8;
    const int tid = threadIdx.x;
    const int cb  = (tid >> 2) * 2;             // even c base (0..126)
    const int hw0 = (tid & 3) * 4;
    const int hw  = tid >> 4, cg = tid & 15;    // read-out mapping
    const float* fb = frames + (size_t)t0 * 2097152 + (size_t)b * 8192;

    float4 pA[4], pB[4], cA[4], cB[4];
    #pragma unroll
    for (int it = 0; it < 4; ++it) {
        const int c = cb + it * 128;
        pA[it] = *reinterpret_cast<const float4*>(fb + c * 16 + hw0);
        pB[it] = *reinterpret_cast<const float4*>(fb + (c + 1) * 16 + hw0);
    }
    #pragma unroll
    for (int dt = 0; dt < 8; ++dt) {
        const float* fc = fb + (size_t)(dt + 1) * 2097152;
        #pragma unroll
        for (int it = 0; it < 4; ++it) {
            const int c = cb + it * 128;
            cA[it] = *reinterpret_cast<const float4*>(fc + c * 16 + hw0);
            cB[it] = *reinterpret_cast<const float4*>(fc + (c + 1) * 16 + hw0);
        }
        #pragma unroll
        for (int it = 0; it < 4; ++it) {
            const int c = cb + it * 128;
            float dA[4], dB[4];
            dA[0] = cA[it].x - pA[it].x; dA[1] = cA[it].y - pA[it].y;
            dA[2] = cA[it].z - pA[it].z; dA[3] = cA[it].w - pA[it].w;
            dB[0] = cB[it].x - pB[it].x; dB[1] = cB[it].y - pB[it].y;
            dB[2] = cB[it].z - pB[it].z; dB[3] = cB[it].w - pB[it].w;
            #pragma unroll
            for (int j = 0; j < 4; ++j)
                *reinterpret_cast<unsigned*>(lds + (hw0 + j) * 1040 + c * 2) = pk2bf(dA[j], dB[j]);
        }
        __syncthreads();
        unsigned short* outp = mdT + ((size_t)((t0 + dt) * 4096 + b * 16 + hw)) * 512;
        #pragma unroll
        for (int r = 0; r < 4; ++r) {
            const int c16 = cg + r * 16;
            const uint4 v = *reinterpret_cast<const uint4*>(lds + hw * 1040 + c16 * 16);
            *reinterpret_cast<uint4*>(outp + c16 * 8) = v;
        }
        __syncthreads();
        #pragma unroll
        for (int it = 0; it < 4; ++it) { pA[it] = cA[it]; pB[it] = cB[it]; }
    }
}

// ---------------- K1: s = leaky(bn(sent @ W_lin^T + b_lin)) -> s_t[j][b] -----------------
__global__ __launch_bounds__(256)
void k1_sent(const float* __restrict__ sent, const float* __restrict__ W_lin,
             const float* __restrict__ b_lin, const float* __restrict__ g_bn_s,
             const float* __restrict__ b_bn_s, float* __restrict__ s_t)
{
    const int j = blockIdx.x;
    const int b = threadIdx.x;
    __shared__ float wl[TXT];
    wl[b] = W_lin[j * TXT + b];
    __syncthreads();
    float acc = b_lin[j];
    const float* srow = sent + b * TXT;
    #pragma unroll 4
    for (int k = 0; k < TXT; k += 4) {
        float4 sv = *reinterpret_cast<const float4*>(srow + k);
        acc = fmaf(sv.x, wl[k], acc);
        acc = fmaf(sv.y, wl[k+1], acc);
        acc = fmaf(sv.z, wl[k+2], acc);
        acc = fmaf(sv.w, wl[k+3], acc);
    }
    float s1 = acc, s2 = acc * acc;
    #pragma unroll
    for (int m = 1; m < 64; m <<= 1) { s1 += __shfl_xor(s1, m, 64); s2 += __shfl_xor(s2, m, 64); }
    __shared__ float r1[4], r2[4];
    if ((b & 63) == 0) { r1[b >> 6] = s1; r2[b >> 6] = s2; }
    __syncthreads();
    const float invN = 1.0f / 256.0f;
    float mean = (r1[0] + r1[1] + r1[2] + r1[3]) * invN;
    float var  = (r2[0] + r2[1] + r2[2] + r2[3]) * invN - mean * mean;
    float rstd = rsqrtf(var + 1e-5f);
    float y = (acc - mean) * rstd * g_bn_s[j] + b_bn_s[j];
    s_t[j * NB + b] = leaky_f(y);
}

// ---------------- K2: sp_bt[b][o] = sum_k s[b,k] * W_p1[o, 512+k] ------------------------
__global__ __launch_bounds__(256)
void k2_sp(const float* __restrict__ s_t, const float* __restrict__ W_p1,
           float* __restrict__ sp_bt)
{
    const int o = blockIdx.x;
    const int b = threadIdx.x;
    __shared__ float wl[TXT];
    wl[b] = W_p1[o * (NC + TXT) + NC + b];
    __syncthreads();
    float acc = 0.0f;
    #pragma unroll 8
    for (int k = 0; k < TXT; ++k)
        acc = fmaf(s_t[k * NB + b], wl[k], acc);
    sp_bt[(size_t)b * NO + o] = acc;
}

// ============ shared GEMM geometry (BK=32, 128x128 tile, 4 blocks/CU) ====================
// row swizzle: physical 16B-chunk = logical ^ ((row>>1)&3).
// ep (epilogue transpose): [128][256B], granule-XOR swizzle g ^= (row&7).

// ---------------- K3: mraw[n][o] = mdT @ WmmBf^T; A 2-buf (L2-hot), B 3-buf (stream) -----
__global__ __launch_bounds__(256, 4)
void k3_mfma(const unsigned short* __restrict__ WmmBf, const unsigned short* __restrict__ mdT,
             unsigned short* __restrict__ mraw,
             float* __restrict__ ssum, float* __restrict__ ssq)
{
    __shared__ __attribute__((aligned(16))) char smem[40960];  // A 2x8K @0; B 3x8K @16384
    const int bx0 = blockIdx.x;
    const int bx = (bx0 & 7) * 512 + (bx0 >> 3);                // XCD swizzle (bijective)
    const int ot = bx & 3, nt = (bx >> 2) & 31, t = bx >> 7;
    const int o0 = ot * 128, n0 = nt * 128;
    const int tid = threadIdx.x;
    const int w = tid >> 6, l = tid & 63;
    const int wo = w >> 1, wn = w & 1;
    const int l15 = l & 15, l16 = l >> 4;

    const char* Ag = (const char*)WmmBf + (size_t)o0 * 1024;
    const char* Bg = (const char*)mdT + ((size_t)(t * 4096 + n0)) * 1024;

    // staging: 2 gl_lds per operand per thread per chunk; instr i covers rows rb=w*32+i*16
    int srcOff[2], dstOff[2];
    #pragma unroll
    for (int i = 0; i < 2; ++i) {
        const int rb = (w << 5) + (i << 4);
        const int row = rb + (l >> 2);
        srcOff[i] = row * 1024 + (((l & 3) ^ ((row >> 1) & 3)) << 4);
        dstOff[i] = rb * 64;
    }

    int offA[4], offB[4];
    #pragma unroll
    for (int m = 0; m < 4; ++m) {
        const int rowA = wo * 64 + m * 16 + l15;
        const int rowB = wn * 64 + m * 16 + l15;
        offA[m] = rowA * 64 + ((l16 ^ ((rowA >> 1) & 3)) << 4);
        offB[m] = rowB * 64 + ((l16 ^ ((rowB >> 1) & 3)) << 4);
    }

    f32x4 acc[4][4];
    #pragma unroll
    for (int i = 0; i < 4; ++i)
        #pragma unroll
        for (int j = 0; j < 4; ++j) acc[i][j] = (f32x4)0.0f;

    auto stageA = [&](int kc, int buf) {
        char* dst = smem + buf * 8192;
        #pragma unroll
        for (int i = 0; i < 2; ++i)
            gl_lds16(Ag + srcOff[i] + kc * 64, dst + dstOff[i]);
    };
    auto stageB = [&](int kc, int buf) {
        char* dst = smem + 16384 + buf * 8192;
        #pragma unroll
        for (int i = 0; i < 2; ++i)
            gl_lds16(Bg + srcOff[i] + kc * 64, dst + dstOff[i]);
    };

    // prologue: A(0),B(0),B(1); wait A(0),B(0) (B(1) stays in flight); barrier
    stageA(0, 0);
    stageB(0, 0);
    stageB(1, 1);
    SB(); WAITV2(); SB(); BAR();

    #pragma unroll
    for (int kc = 0; kc < 16; ++kc) {
        const int acur = (kc & 1) * 8192;
        const int bcur = 16384 + (kc % 3) * 8192;
        if (kc < 15) stageA(kc + 1, (kc + 1) & 1);
        if (kc < 14) stageB(kc + 2, (kc + 2) % 3);
        SB();
        {
            bf16x8 a[4], b[4];
            #pragma unroll
            for (int m = 0; m < 4; ++m) a[m] = *reinterpret_cast<const bf16x8*>(smem + acur + offA[m]);
            #pragma unroll
            for (int n = 0; n < 4; ++n) b[n] = *reinterpret_cast<const bf16x8*>(smem + bcur + offB[n]);
            #pragma unroll
            for (int m = 0; m < 4; ++m)
                #pragma unroll
                for (int n = 0; n < 4; ++n)
                    acc[m][n] = __builtin_amdgcn_mfma_f32_16x16x32_bf16(a[m], b[n], acc[m][n], 0, 0, 0);
        }
        SB();
        // FIFO end-of-chunk: drains B(kc+1)+A(kc+1), leaves B(kc+2)x2 in flight
        if (kc <= 13)      { WAITV2(); }
        else if (kc == 14) { WAITV0(); }
        else               { WAITL();  }
        SB();
        BAR();
    }

    // stats from registers: D row = o = 4*l16 + r (+m*16), col = n = l15 (+nn*16)
    #pragma unroll
    for (int m = 0; m < 4; ++m) {
        #pragma unroll
        for (int r = 0; r < 4; ++r) {
            float s1 = 0.0f, s2 = 0.0f;
            #pragma unroll
            for (int nn = 0; nn < 4; ++nn) {
                const float v = acc[m][nn][r];
                s1 += v; s2 = fmaf(v, v, s2);
            }
            #pragma unroll
            for (int msk = 1; msk < 16; msk <<= 1) {
                s1 += __shfl_xor(s1, msk, 64);
                s2 += __shfl_xor(s2, msk, 64);
            }
            if (l15 == 0) {
                const int o = o0 + wo * 64 + m * 16 + (l16 << 2) + r;
                atomicAdd(&ssum[t * NO + o], s1);
                atomicAdd(&ssq[t * NO + o], s2);
            }
        }
    }

    // epilogue: acc -> ep[n:128][o-granule XOR-swz] -> coalesced global [n][o]
    char* ep = smem;
    #pragma unroll
    for (int m = 0; m < 4; ++m) {
        #pragma unroll
        for (int nn = 0; nn < 4; ++nn) {
            uint2 u;
            u.x = pk2bf(acc[m][nn][0], acc[m][nn][1]);
            u.y = pk2bf(acc[m][nn][2], acc[m][nn][3]);
            const int row = wn * 64 + nn * 16 + l15;
            const int g   = wo * 8 + m * 2 + (l16 >> 1);       // 16B granule (o-block)
            const int off = row * 256 + ((g ^ (row & 7)) << 4) + ((l16 & 1) << 3);
            *reinterpret_cast<uint2*>(ep + off) = u;
        }
    }
    SB(); WAITL(); SB(); BAR();
    #pragma unroll
    for (int p = 0; p < 8; ++p) {
        const int row = (p << 4) + (tid >> 4);
        const int c   = tid & 15;
        const uint4 v = *reinterpret_cast<const uint4*>(ep + row * 256 + ((c ^ (row & 7)) << 4));
        *reinterpret_cast<uint4*>((char*)mraw + ((size_t)(t * 4096 + n0 + row)) * 1024
                                  + o0 * 2 + (c << 4)) = v;
    }
}

// ---------------- K4/K6: finalize stats -> alpha/beta ------------------------------------
__global__ __launch_bounds__(256)
void kstats(const float* __restrict__ ssum, const float* __restrict__ ssq,
            const float* __restrict__ g, const float* __restrict__ bb,
            float* __restrict__ alpha, float* __restrict__ beta)
{
    const int i = blockIdx.x * 256 + threadIdx.x;  // t*512+o
    const int o = i & 511;
    const float invN = 1.0f / 4096.0f;
    float mean = ssum[i] * invN;
    float var  = ssq[i] * invN - mean * mean;
    float rstd = rsqrtf(var + 1e-5f);
    float a = rstd * g[o];
    alpha[i] = a;
    beta[i]  = fmaf(-mean, a, bb[o]);
}

// ---------------- K5: praw[n][o] = leaky(bn(mraw)) @ Wp1bf^T + sp ------------------------
// A: gl_lds 2-buf (L2-hot, 1-ahead). B: reg-staged 3-ahead (ur[3]) + procB -> Bt 2 bufs.
// Steady end-of-chunk wait vmcnt(2): drains u(kc+2)+A(kc+1), leaves u(kc+3)x2 in flight.
__global__ __launch_bounds__(256, 4)
void k5_mfma(const unsigned short* __restrict__ Wp1Bf, const unsigned short* __restrict__ mraw,
             const float* __restrict__ am, const float* __restrict__ bm,
             const float* __restrict__ sp_bt,
             unsigned short* __restrict__ praw,
             float* __restrict__ ssum, float* __restrict__ ssq)
{
    __shared__ __attribute__((aligned(16))) char smem[36864];
    // A bufs: 0 / 8192 ; Bt bufs: 16384 / 24576 ; alf 32768 ; bet 34816
    float* alf = (float*)(smem + 32768);
    float* bet = (float*)(smem + 34816);
    const int bx0 = blockIdx.x;
    const int bx = (bx0 & 7) * 512 + (bx0 >> 3);                // XCD swizzle (bijective)
    const int ot = bx & 3, nt = (bx >> 2) & 31, t = bx >> 7;
    const int o0 = ot * 128, n0 = nt * 128;
    const int tid = threadIdx.x;
    const int w = tid >> 6, l = tid & 63;
    const int wo = w >> 1, wn = w & 1;
    const int l15 = l & 15, l16 = l >> 4;

    const char* Ag = (const char*)Wp1Bf + (size_t)o0 * 1024;

    int srcOffA[2], dstOffA[2];
    #pragma unroll
    for (int i = 0; i < 2; ++i) {
        const int rb = (w << 5) + (i << 4);
        const int row = rb + (l >> 2);
        srcOffA[i] = row * 1024 + (((l & 3) ^ ((row >> 1) & 3)) << 4);
        dstOffA[i] = rb * 64;
    }

    const int rowB_s = tid >> 1, h = tid & 1;
    const char* mrow = (const char*)mraw + ((size_t)(t * 4096 + n0 + rowB_s)) * 1024 + h * 32;
    const int bbase = rowB_s * 64;
    const int bswz = (rowB_s >> 1) & 3;

    int offA[4], offB[4];
    #pragma unroll
    for (int m = 0; m < 4; ++m) {
        const int rowA = wo * 64 + m * 16 + l15;
        const int rowB = wn * 64 + m * 16 + l15;
        offA[m] = rowA * 64 + ((l16 ^ ((rowA >> 1) & 3)) << 4);
        offB[m] = rowB * 64 + ((l16 ^ ((rowB >> 1) & 3)) << 4);
    }

    f32x4 acc[4][4];
    #pragma unroll
    for (int i = 0; i < 4; ++i)
        #pragma unroll
        for (int j = 0; j < 4; ++j) acc[i][j] = (f32x4)0.0f;

    ushort8 ur[3][2];

    auto gldsA = [&](int kc, int buf) {
        char* dst = smem + buf * 8192;
        #pragma unroll
        for (int i = 0; i < 2; ++i)
            gl_lds16(Ag + srcOffA[i] + kc * 64, dst + dstOffA[i]);
    };
    auto loadU = [&](int slot, int kc) {
        #pragma unroll
        for (int q = 0; q < 2; ++q)
            ur[slot][q] = *reinterpret_cast<const ushort8*>(mrow + kc * 64 + q * 16);
    };
    // procB (packed): affine+leaky on ur[slot] (chunk kc), pack bf16, swizzled ds_write
    auto procB = [&](int slot, int kc, int btoff) {
        const f32x2 c02 = {0.2f, 0.2f};
        #pragma unroll
        for (int q = 0; q < 2; ++q) {
            const int kbase = kc * 32 + h * 16 + q * 8;
            const uint4 uw = *reinterpret_cast<const uint4*>(&ur[slot][q]);
            const unsigned wd[4] = {uw.x, uw.y, uw.z, uw.w};
            unsigned pko[4];
            #pragma unroll
            for (int p = 0; p < 4; ++p) {
                f32x2 x;
                x.x = __uint_as_float(wd[p] << 16);
                x.y = __uint_as_float(wd[p] & 0xffff0000u);
                const f32x2 al = *reinterpret_cast<const f32x2*>(alf + kbase + p * 2);
                const f32x2 be = *reinterpret_cast<const f32x2*>(bet + kbase + p * 2);
                const f32x2 y = pk_fma2(x, al, be);
                const f32x2 z = pk_mul2(y, c02);
                pko[p] = pk2bf(fmaxf(y.x, z.x), fmaxf(y.y, z.y));
            }
            uint4 pk = {pko[0], pko[1], pko[2], pko[3]};
            *reinterpret_cast<uint4*>(smem + btoff + bbase + ((((h << 1) + q) ^ bswz) << 4)) = pk;
        }
    };

    // prologue (FIFO order): u0; A(0); u1; u2. lgkm-only barrier (alf/bet visibility,
    // vmem stays in flight); procB(0) auto-waits u0; WAITV4 drains A(0), leaves u1,u2.
    {
        const float* amt = am + t * NC;
        const float* bmt = bm + t * NC;
        const float2 a2 = *reinterpret_cast<const float2*>(amt + tid * 2);
        const float2 b2 = *reinterpret_cast<const float2*>(bmt + tid * 2);
        *reinterpret_cast<float2*>(alf + tid * 2) = a2;
        *reinterpret_cast<float2*>(bet + tid * 2) = b2;
    }
    loadU(0, 0);
    gldsA(0, 0);
    loadU(1, 1);
    loadU(2, 2);
    SB(); WAITL(); SB(); BAR();          // alf/bet visible; vmcnt untouched
    procB(0, 0, 16384);                  // auto-waits u0 only (oldest)
    SB(); WAITV4(); SB(); BAR();         // A(0) done; u1,u2 stay in flight

    #pragma unroll
    for (int kc = 0; kc < 16; ++kc) {
        const int acur = (kc & 1) * 8192;
        const int bcur = 16384 + (kc & 1) * 8192;
        if (kc < 15) gldsA(kc + 1, (kc + 1) & 1);
        SB();
        if (kc < 15) procB((kc + 1) % 3, kc + 1, 16384 + ((kc + 1) & 1) * 8192);
        if (kc < 13) loadU(kc % 3, kc + 3);          // (kc+3)%3 == kc%3
        SB();
        {
            bf16x8 a[4], b[4];
            #pragma unroll
            for (int m = 0; m < 4; ++m) a[m] = *reinterpret_cast<const bf16x8*>(smem + acur + offA[m]);
            #pragma unroll
            for (int n = 0; n < 4; ++n) b[n] = *reinterpret_cast<const bf16x8*>(smem + bcur + offB[n]);
            #pragma unroll
            for (int m = 0; m < 4; ++m)
                #pragma unroll
                for (int n = 0; n < 4; ++n)
                    acc[m][n] = __builtin_amdgcn_mfma_f32_16x16x32_bf16(a[m], b[n], acc[m][n], 0, 0, 0);
        }
        SB();
        // steady: drains u(kc+2)+A(kc+1), leaves u(kc+3)x2
        if (kc <= 12)      { WAITV2(); }
        else if (kc <= 14) { WAITV0(); }
        else               { WAITL();  }
        SB();
        BAR();
    }

    // epilogue: +sp, stats, ep transpose (granule XOR), coalesced store
    char* ep = smem;
    #pragma unroll
    for (int m = 0; m < 4; ++m) {
        const int oc = o0 + wo * 64 + m * 16 + (l16 << 2);
        float s1[4] = {0,0,0,0}, s2[4] = {0,0,0,0};
        #pragma unroll
        for (int nn = 0; nn < 4; ++nn) {
            const int b = (n0 >> 4) + wn * 4 + nn;
            const float4 sp4 = *reinterpret_cast<const float4*>(sp_bt + (size_t)b * NO + oc);
            const float spv[4] = {sp4.x, sp4.y, sp4.z, sp4.w};
            float pv[4];
            #pragma unroll
            for (int r = 0; r < 4; ++r) {
                const float v = acc[m][nn][r] + spv[r];
                pv[r] = v;
                s1[r] += v; s2[r] = fmaf(v, v, s2[r]);
            }
            uint2 uu;
            uu.x = pk2bf(pv[0], pv[1]);
            uu.y = pk2bf(pv[2], pv[3]);
            const int row = wn * 64 + nn * 16 + l15;
            const int g   = wo * 8 + m * 2 + (l16 >> 1);
            const int off = row * 256 + ((g ^ (row & 7)) << 4) + ((l16 & 1) << 3);
            *reinterpret_cast<uint2*>(ep + off) = uu;
        }
        #pragma unroll
        for (int r = 0; r < 4; ++r) {
            #pragma unroll
            for (int msk = 1; msk < 16; msk <<= 1) {
                s1[r] += __shfl_xor(s1[r], msk, 64);
                s2[r] += __shfl_xor(s2[r], msk, 64);
            }
            if (l15 == 0) {
                atomicAdd(&ssum[t * NO + oc + r], s1[r]);
                atomicAdd(&ssq[t * NO + oc + r], s2[r]);
            }
        }
    }
    SB(); WAITL(); SB(); BAR();
    #pragma unroll
    for (int p = 0; p < 8; ++p) {
        const int row = (p << 4) + (tid >> 4);
        const int c   = tid & 15;
        const uint4 v = *reinterpret_cast<const uint4*>(ep + row * 256 + ((c ^ (row & 7)) << 4));
        *reinterpret_cast<uint4*>((char*)praw + ((size_t)(t * 4096 + n0 + row)) * 1024
                                  + o0 * 2 + (c << 4)) = v;
    }
}

// ---------------- K7: out[t,b] = sigmoid(sum leaky(bn(praw)) * Wp2) ----------------------
// Lane owns a fixed o-slice (o8..o8+7); hw varies per e. ap/bp loads hoisted out of loop.
__global__ __launch_bounds__(256)
void k7_out(const unsigned short* __restrict__ praw, const float* __restrict__ ap,
            const float* __restrict__ bp, const float* __restrict__ wp2t,
            float* __restrict__ out)
{
    const int bx = blockIdx.x;
    const int t = bx >> 8, b = bx & 255;
    const int tid = threadIdx.x;
    const int o8 = (tid & 63) * 8;
    const int hwq = tid >> 6;            // wave id 0..3
    const unsigned short* pr = praw + ((size_t)(t * 256 + b)) * 8192;  // [hw][o]

    float av[8], bv[8];
    *reinterpret_cast<float4*>(av)     = *reinterpret_cast<const float4*>(ap + t * NO + o8);
    *reinterpret_cast<float4*>(av + 4) = *reinterpret_cast<const float4*>(ap + t * NO + o8 + 4);
    *reinterpret_cast<float4*>(bv)     = *reinterpret_cast<const float4*>(bp + t * NO + o8);
    *reinterpret_cast<float4*>(bv + 4) = *reinterpret_cast<const float4*>(bp + t * NO + o8 + 4);

    float acc = 0.0f;
    #pragma unroll
    for (int e = 0; e < 4; ++e) {
        const int hw = hwq + e * 4;
        const ushort8 u = *reinterpret_cast<const ushort8*>(pr + hw * 512 + o8);
        float wv[8];
        *reinterpret_cast<float4*>(wv)     = *reinterpret_cast<const float4*>(wp2t + hw * NO + o8);
        *reinterpret_cast<float4*>(wv + 4) = *reinterpret_cast<const float4*>(wp2t + hw * NO + o8 + 4);
        #pragma unroll
        for (int j = 0; j < 8; ++j) {
            const float x = leaky_f(fmaf(bf2f(u[j]), av[j], bv[j]));
            acc = fmaf(x, wv[j], acc);
        }
    }
    #pragma unroll
    for (int m = 1; m < 64; m <<= 1) acc += __shfl_xor(acc, m, 64);
    __shared__ float red[4];
    if ((tid & 63) == 0) red[tid >> 6] = acc;
    __syncthreads();
    if (tid == 0) {
        float z = red[0] + red[1] + red[2] + red[3];
        out[t * NB + b] = 1.0f / (1.0f + __expf(-z));
    }
}

// ------------------------------------------------------------------------------------------
extern "C" void kernel_launch(void* const* d_in, const int* in_sizes, int n_in,
                              void* d_out, int out_size, void* d_ws, size_t ws_size,
                              hipStream_t stream)
{
    const float* frames = (const float*)d_in[0];
    const float* sent   = (const float*)d_in[1];
    const float* W_lin  = (const float*)d_in[2];
    const float* b_lin  = (const float*)d_in[3];
    const float* g_bn_s = (const float*)d_in[4];
    const float* b_bn_s = (const float*)d_in[5];
    const float* W_mm   = (const float*)d_in[6];
    const float* g_bn_m = (const float*)d_in[7];
    const float* b_bn_m = (const float*)d_in[8];
    const float* W_p1   = (const float*)d_in[9];
    const float* g_bn_p = (const float*)d_in[10];
    const float* b_bn_p = (const float*)d_in[11];
    const float* W_p2   = (const float*)d_in[12];
    float* out = (float*)d_out;

    char* ws = (char*)d_ws;
    const size_t BIG = 134217728;                    // 32*256*16*512*2
    unsigned short* bufA = (unsigned short*)ws;      // mdT, later praw (aliased)
    unsigned short* bufB = (unsigned short*)(ws + BIG);  // mraw
    char* small = ws + 2 * BIG;
    float* msum = (float*)(small);                   // 16384 f32 each
    float* msq  = (float*)(small + 65536);
    float* psum = (float*)(small + 131072);
    float* psq  = (float*)(small + 196608);
    float* am   = (float*)(small + 262144);
    float* bm   = (float*)(small + 327680);
    float* apv  = (float*)(small + 393216);
    float* bpv  = (float*)(small + 458752);
    float* s_t  = (float*)(small + 524288);          // 256*256 f32
    float* sp_bt= (float*)(small + 786432);          // 256*512 f32
    float* wp2t = (float*)(small + 1310720);         // 16*512 f32
    unsigned short* WmmBf = (unsigned short*)(small + 1343488);  // 512*512 bf16
    unsigned short* Wp1Bf = (unsigned short*)(small + 1867776);  // 512*512 bf16

    hipMemsetAsync(small, 0, 262144, stream);
    kprep_w<<<1056, 256, 0, stream>>>(W_mm, W_p1, W_p2, WmmBf, Wp1Bf, wp2t);
    kprep_diff<<<1024, 256, 0, stream>>>(frames, bufA);
    k1_sent<<<256, 256, 0, stream>>>(sent, W_lin, b_lin, g_bn_s, b_bn_s, s_t);
    k2_sp<<<512, 256, 0, stream>>>(s_t, W_p1, sp_bt);
    k3_mfma<<<4096, 256, 0, stream>>>(WmmBf, bufA, bufB, msum, msq);
    kstats<<<64, 256, 0, stream>>>(msum, msq, g_bn_m, b_bn_m, am, bm);
    k5_mfma<<<4096, 256, 0, stream>>>(Wp1Bf, bufB, am, bm, sp_bt, bufA, psum, psq);
    kstats<<<64, 256, 0, stream>>>(psum, psq, g_bn_p, b_bn_p, apv, bpv);
    k7_out<<<8192, 256, 0, stream>>>(bufA, apv, bpv, wp2t, out);
}

// Round 11
// 424.500 us; speedup vs baseline: 1.0573x; 1.0573x over previous
//
#include <hip/hip_runtime.h>
#include <hip/hip_bf16.h>

typedef __attribute__((ext_vector_type(8))) unsigned short ushort8;
typedef __attribute__((ext_vector_type(8))) short bf16x8;
typedef __attribute__((ext_vector_type(4))) float f32x4;

#define TM 32      // motion frames
#define NB 256     // batch
#define NC 512     // channels in
#define NO 512     // channels out
#define HW 16      // H*W
#define TXT 256

#define SB()     __builtin_amdgcn_sched_barrier(0)
#define BAR()    __builtin_amdgcn_s_barrier()
#define PRIO1()  __builtin_amdgcn_s_setprio(1)
#define PRIO0()  __builtin_amdgcn_s_setprio(0)
#define WAITV6() asm volatile("s_waitcnt vmcnt(6) lgkmcnt(0)" ::: "memory")
#define WAITV4() asm volatile("s_waitcnt vmcnt(4) lgkmcnt(0)" ::: "memory")
#define WAITV0() asm volatile("s_waitcnt vmcnt(0) lgkmcnt(0)" ::: "memory")
#define WAITL()  asm volatile("s_waitcnt lgkmcnt(0)" ::: "memory")

__device__ __forceinline__ float bf2f(unsigned short u) {
    return __uint_as_float(((unsigned)u) << 16);
}
__device__ __forceinline__ unsigned pk2bf(float lo, float hi) {
    __hip_bfloat162 h = __float22bfloat162_rn(float2{lo, hi});
    return *reinterpret_cast<unsigned*>(&h);
}
__device__ __forceinline__ float leaky_f(float x) { return fmaxf(x, 0.2f * x); }

__device__ __forceinline__ void gl_lds16(const void* g, void* l) {
    __builtin_amdgcn_global_load_lds(
        (const __attribute__((address_space(1))) unsigned int*)g,
        (__attribute__((address_space(3))) unsigned int*)l, 16, 0, 0);
}

// ---------------- K0a: weights -> bf16 (+ Wp2 transpose) ---------------------------------
__global__ __launch_bounds__(256)
void kprep_w(const float* __restrict__ Wmm, const float* __restrict__ Wp1,
             const float* __restrict__ Wp2,
             unsigned short* __restrict__ WmmBf, unsigned short* __restrict__ Wp1Bf,
             float* __restrict__ Wp2T)
{
    const int bid = blockIdx.x, tid = threadIdx.x;
    if (bid < 512) {
        const float2 v = *reinterpret_cast<const float2*>(Wmm + (size_t)bid * 512 + tid * 2);
        ((unsigned*)WmmBf)[bid * 256 + tid] = pk2bf(v.x, v.y);
    } else if (bid < 1024) {
        const int o = bid - 512;
        const float2 v = *reinterpret_cast<const float2*>(Wp1 + (size_t)o * 768 + tid * 2);
        ((unsigned*)Wp1Bf)[o * 256 + tid] = pk2bf(v.x, v.y);
    } else {
        const int i = (bid - 1024) * 256 + tid;   // 0..8191
        const int hw = i >> 9, o = i & 511;
        Wp2T[i] = Wp2[o * 16 + hw];
    }
}

// ---------------- K0b: motion diff (8 t per block), LDS transpose, coalesced R/W ---------
__global__ __launch_bounds__(256)
void kprep_diff(const float* __restrict__ frames, unsigned short* __restrict__ mdT)
{
    __shared__ __attribute__((aligned(16))) char lds[16 * 1040];
    const int bx = blockIdx.x;
    const int tg = bx >> 8, b = bx & 255;       // tg 0..3 -> t = tg*8 .. +7
    const int t0 = tg * 8;
    const int tid = threadIdx.x;
    const int cb  = (tid >> 2) * 2;             // even c base (0..126)
    const int hw0 = (tid & 3) * 4;
    const int hw  = tid >> 4, cg = tid & 15;    // read-out mapping
    const float* fb = frames + (size_t)t0 * 2097152 + (size_t)b * 8192;

    float4 pA[4], pB[4], cA[4], cB[4];
    #pragma unroll
    for (int it = 0; it < 4; ++it) {
        const int c = cb + it * 128;
        pA[it] = *reinterpret_cast<const float4*>(fb + c * 16 + hw0);
        pB[it] = *reinterpret_cast<const float4*>(fb + (c + 1) * 16 + hw0);
    }
    #pragma unroll
    for (int dt = 0; dt < 8; ++dt) {
        const float* fc = fb + (size_t)(dt + 1) * 2097152;
        #pragma unroll
        for (int it = 0; it < 4; ++it) {
            const int c = cb + it * 128;
            cA[it] = *reinterpret_cast<const float4*>(fc + c * 16 + hw0);
            cB[it] = *reinterpret_cast<const float4*>(fc + (c + 1) * 16 + hw0);
        }
        #pragma unroll
        for (int it = 0; it < 4; ++it) {
            const int c = cb + it * 128;
            float dA[4], dB[4];
            dA[0] = cA[it].x - pA[it].x; dA[1] = cA[it].y - pA[it].y;
            dA[2] = cA[it].z - pA[it].z; dA[3] = cA[it].w - pA[it].w;
            dB[0] = cB[it].x - pB[it].x; dB[1] = cB[it].y - pB[it].y;
            dB[2] = cB[it].z - pB[it].z; dB[3] = cB[it].w - pB[it].w;
            #pragma unroll
            for (int j = 0; j < 4; ++j)
                *reinterpret_cast<unsigned*>(lds + (hw0 + j) * 1040 + c * 2) = pk2bf(dA[j], dB[j]);
        }
        __syncthreads();
        unsigned short* outp = mdT + ((size_t)((t0 + dt) * 4096 + b * 16 + hw)) * 512;
        #pragma unroll
        for (int r = 0; r < 4; ++r) {
            const int c16 = cg + r * 16;
            const uint4 v = *reinterpret_cast<const uint4*>(lds + hw * 1040 + c16 * 16);
            *reinterpret_cast<uint4*>(outp + c16 * 8) = v;
        }
        __syncthreads();
        #pragma unroll
        for (int it = 0; it < 4; ++it) { pA[it] = cA[it]; pB[it] = cB[it]; }
    }
}

// ---------------- K1: s = leaky(bn(sent @ W_lin^T + b_lin)) -> s_t[j][b] -----------------
__global__ __launch_bounds__(256)
void k1_sent(const float* __restrict__ sent, const float* __restrict__ W_lin,
             const float* __restrict__ b_lin, const float* __restrict__ g_bn_s,
             const float* __restrict__ b_bn_s, float* __restrict__ s_t)
{
    const int j = blockIdx.x;
    const int b = threadIdx.x;
    __shared__ float wl[TXT];
    wl[b] = W_lin[j * TXT + b];
    __syncthreads();
    float acc = b_lin[j];
    const float* srow = sent + b * TXT;
    #pragma unroll 4
    for (int k = 0; k < TXT; k += 4) {
        float4 sv = *reinterpret_cast<const float4*>(srow + k);
        acc = fmaf(sv.x, wl[k], acc);
        acc = fmaf(sv.y, wl[k+1], acc);
        acc = fmaf(sv.z, wl[k+2], acc);
        acc = fmaf(sv.w, wl[k+3], acc);
    }
    float s1 = acc, s2 = acc * acc;
    #pragma unroll
    for (int m = 1; m < 64; m <<= 1) { s1 += __shfl_xor(s1, m, 64); s2 += __shfl_xor(s2, m, 64); }
    __shared__ float r1[4], r2[4];
    if ((b & 63) == 0) { r1[b >> 6] = s1; r2[b >> 6] = s2; }
    __syncthreads();
    const float invN = 1.0f / 256.0f;
    float mean = (r1[0] + r1[1] + r1[2] + r1[3]) * invN;
    float var  = (r2[0] + r2[1] + r2[2] + r2[3]) * invN - mean * mean;
    float rstd = rsqrtf(var + 1e-5f);
    float y = (acc - mean) * rstd * g_bn_s[j] + b_bn_s[j];
    s_t[j * NB + b] = leaky_f(y);
}

// ---------------- K2: sp_bt[b][o] = sum_k s[b,k] * W_p1[o, 512+k] ------------------------
__global__ __launch_bounds__(256)
void k2_sp(const float* __restrict__ s_t, const float* __restrict__ W_p1,
           float* __restrict__ sp_bt)
{
    const int o = blockIdx.x;
    const int b = threadIdx.x;
    __shared__ float wl[TXT];
    wl[b] = W_p1[o * (NC + TXT) + NC + b];
    __syncthreads();
    float acc = 0.0f;
    #pragma unroll 8
    for (int k = 0; k < TXT; ++k)
        acc = fmaf(s_t[k * NB + b], wl[k], acc);
    sp_bt[(size_t)b * NO + o] = acc;
}

// ============ shared GEMM geometry (BK=32, 128x128 tile) =================================
// per K-buffer: At[128][32] bf16 (8KB) + Bt[128][32] bf16 (8KB).
// row swizzle: physical 16B-chunk = logical ^ ((row>>1)&3).
// ep (epilogue transpose): [128][256B], granule-XOR swizzle g ^= (row&7).

// ---------------- K3: mraw[n][o] = mdT @ WmmBf^T; A+B both gl_lds, 3-deep rotation -------
__global__ __launch_bounds__(256, 3)
void k3_mfma(const unsigned short* __restrict__ WmmBf, const unsigned short* __restrict__ mdT,
             unsigned short* __restrict__ mraw,
             float* __restrict__ ssum, float* __restrict__ ssq)
{
    __shared__ __attribute__((aligned(16))) char smem[49152];   // 3 x (At 8K + Bt 8K)
    const int bx0 = blockIdx.x;
    const int bx = (bx0 & 7) * 512 + (bx0 >> 3);                // XCD swizzle (bijective)
    const int ot = bx & 3, nt = (bx >> 2) & 31, t = bx >> 7;
    const int o0 = ot * 128, n0 = nt * 128;
    const int tid = threadIdx.x;
    const int w = tid >> 6, l = tid & 63;
    const int wo = w >> 1, wn = w & 1;
    const int l15 = l & 15, l16 = l >> 4;

    const char* Ag = (const char*)WmmBf + (size_t)o0 * 1024;
    const char* Bg = (const char*)mdT + ((size_t)(t * 4096 + n0)) * 1024;

    // staging: 2 gl_lds per operand per thread per chunk; instr i covers rows rb=w*32+i*16
    int srcOff[2], dstOff[2];
    #pragma unroll
    for (int i = 0; i < 2; ++i) {
        const int rb = (w << 5) + (i << 4);
        const int row = rb + (l >> 2);
        srcOff[i] = row * 1024 + (((l & 3) ^ ((row >> 1) & 3)) << 4);
        dstOff[i] = rb * 64;
    }

    int offA[4], offB[4];
    #pragma unroll
    for (int m = 0; m < 4; ++m) {
        const int rowA = wo * 64 + m * 16 + l15;
        const int rowB = wn * 64 + m * 16 + l15;
        offA[m] = rowA * 64 + ((l16 ^ ((rowA >> 1) & 3)) << 4);
        offB[m] = 8192 + rowB * 64 + ((l16 ^ ((rowB >> 1) & 3)) << 4);
    }

    f32x4 acc[4][4];
    #pragma unroll
    for (int i = 0; i < 4; ++i)
        #pragma unroll
        for (int j = 0; j < 4; ++j) acc[i][j] = (f32x4)0.0f;

    auto stage = [&](int kc, int buf) {
        char* dst = smem + buf * 16384;
        #pragma unroll
        for (int i = 0; i < 2; ++i)
            gl_lds16(Ag + srcOff[i] + kc * 64, dst + dstOff[i]);
        #pragma unroll
        for (int i = 0; i < 2; ++i)
            gl_lds16(Bg + srcOff[i] + kc * 64, dst + 8192 + dstOff[i]);
    };

    // prologue: stage(0), stage(1); wait stage(0) (4 newest in flight); barrier
    stage(0, 0);
    stage(1, 1);
    SB(); WAITV4(); SB(); BAR();

    #pragma unroll
    for (int kc = 0; kc < 16; ++kc) {
        const int cur = (kc % 3) * 16384;
        if (kc < 14) stage(kc + 2, (kc + 2) % 3);
        SB();
        {
            bf16x8 a[4], b[4];
            #pragma unroll
            for (int m = 0; m < 4; ++m) a[m] = *reinterpret_cast<const bf16x8*>(smem + cur + offA[m]);
            #pragma unroll
            for (int n = 0; n < 4; ++n) b[n] = *reinterpret_cast<const bf16x8*>(smem + cur + offB[n]);
            PRIO1();
            #pragma unroll
            for (int m = 0; m < 4; ++m)
                #pragma unroll
                for (int n = 0; n < 4; ++n)
                    acc[m][n] = __builtin_amdgcn_mfma_f32_16x16x32_bf16(a[m], b[n], acc[m][n], 0, 0, 0);
            PRIO0();
        }
        SB();
        if (kc < 14)       { WAITV4(); }
        else if (kc == 14) { WAITV0(); }
        else               { WAITL();  }
        SB();
        BAR();
    }

    // stats from registers: D row = o = 4*l16 + r (+m*16), col = n = l15 (+nn*16)
    #pragma unroll
    for (int m = 0; m < 4; ++m) {
        #pragma unroll
        for (int r = 0; r < 4; ++r) {
            float s1 = 0.0f, s2 = 0.0f;
            #pragma unroll
            for (int nn = 0; nn < 4; ++nn) {
                const float v = acc[m][nn][r];
                s1 += v; s2 = fmaf(v, v, s2);
            }
            #pragma unroll
            for (int msk = 1; msk < 16; msk <<= 1) {
                s1 += __shfl_xor(s1, msk, 64);
                s2 += __shfl_xor(s2, msk, 64);
            }
            if (l15 == 0) {
                const int o = o0 + wo * 64 + m * 16 + (l16 << 2) + r;
                atomicAdd(&ssum[t * NO + o], s1);
                atomicAdd(&ssq[t * NO + o], s2);
            }
        }
    }

    // epilogue: acc -> ep[n:128][o-granule XOR-swz] -> coalesced global [n][o]
    char* ep = smem;
    #pragma unroll
    for (int m = 0; m < 4; ++m) {
        #pragma unroll
        for (int nn = 0; nn < 4; ++nn) {
            uint2 u;
            u.x = pk2bf(acc[m][nn][0], acc[m][nn][1]);
            u.y = pk2bf(acc[m][nn][2], acc[m][nn][3]);
            const int row = wn * 64 + nn * 16 + l15;
            const int g   = wo * 8 + m * 2 + (l16 >> 1);       // 16B granule (o-block)
            const int off = row * 256 + ((g ^ (row & 7)) << 4) + ((l16 & 1) << 3);
            *reinterpret_cast<uint2*>(ep + off) = u;
        }
    }
    SB(); WAITL(); SB(); BAR();
    #pragma unroll
    for (int p = 0; p < 8; ++p) {
        const int row = (p << 4) + (tid >> 4);
        const int c   = tid & 15;
        const uint4 v = *reinterpret_cast<const uint4*>(ep + row * 256 + ((c ^ (row & 7)) << 4));
        *reinterpret_cast<uint4*>((char*)mraw + ((size_t)(t * 4096 + n0 + row)) * 1024
                                  + o0 * 2 + (c << 4)) = v;
    }
}

// ---------------- K4/K6: finalize stats -> alpha/beta ------------------------------------
__global__ __launch_bounds__(256)
void kstats(const float* __restrict__ ssum, const float* __restrict__ ssq,
            const float* __restrict__ g, const float* __restrict__ bb,
            float* __restrict__ alpha, float* __restrict__ beta)
{
    const int i = blockIdx.x * 256 + threadIdx.x;  // t*512+o
    const int o = i & 511;
    const float invN = 1.0f / 4096.0f;
    float mean = ssum[i] * invN;
    float var  = ssq[i] * invN - mean * mean;
    float rstd = rsqrtf(var + 1e-5f);
    float a = rstd * g[o];
    alpha[i] = a;
    beta[i]  = fmaf(-mean, a, bb[o]);
}

// ---------------- K5: praw[n][o] = leaky(bn(mraw)) @ Wp1bf^T + sp ------------------------
// A: gl_lds 2-ahead (3 bufs). B: reg-staged 3-ahead (ur[3]) + procB -> Bt 2 bufs.
// Per-chunk issue order: gldsA(kc+2) -> procB(kc+1) -> u(kc+3); wait vmcnt(6) keeps
// the 6 newest (u(kc+2), gldsA(kc+2), u(kc+3)) in flight across the barrier.
__global__ __launch_bounds__(256, 3)
void k5_mfma(const unsigned short* __restrict__ Wp1Bf, const unsigned short* __restrict__ mraw,
             const float* __restrict__ am, const float* __restrict__ bm,
             const float* __restrict__ sp_bt,
             unsigned short* __restrict__ praw,
             float* __restrict__ ssum, float* __restrict__ ssq)
{
    __shared__ __attribute__((aligned(16))) char smem[45056];
    // A bufs: 0 / 8192 / 16384 ; Bt bufs: 24576 + parity*8192 ; alf 40960 ; bet 43008
    float* alf = (float*)(smem + 40960);
    float* bet = (float*)(smem + 43008);
    const int bx0 = blockIdx.x;
    const int bx = (bx0 & 7) * 512 + (bx0 >> 3);                // XCD swizzle (bijective)
    const int ot = bx & 3, nt = (bx >> 2) & 31, t = bx >> 7;
    const int o0 = ot * 128, n0 = nt * 128;
    const int tid = threadIdx.x;
    const int w = tid >> 6, l = tid & 63;
    const int wo = w >> 1, wn = w & 1;
    const int l15 = l & 15, l16 = l >> 4;

    const char* Ag = (const char*)Wp1Bf + (size_t)o0 * 1024;

    int srcOffA[2], dstOffA[2];
    #pragma unroll
    for (int i = 0; i < 2; ++i) {
        const int rb = (w << 5) + (i << 4);
        const int row = rb + (l >> 2);
        srcOffA[i] = row * 1024 + (((l & 3) ^ ((row >> 1) & 3)) << 4);
        dstOffA[i] = rb * 64;
    }

    const int rowB_s = tid >> 1, h = tid & 1;
    const char* mrow = (const char*)mraw + ((size_t)(t * 4096 + n0 + rowB_s)) * 1024 + h * 32;
    const int bbase = rowB_s * 64;
    const int bswz = (rowB_s >> 1) & 3;

    int offA[4], offB[4];
    #pragma unroll
    for (int m = 0; m < 4; ++m) {
        const int rowA = wo * 64 + m * 16 + l15;
        const int rowB = wn * 64 + m * 16 + l15;
        offA[m] = rowA * 64 + ((l16 ^ ((rowA >> 1) & 3)) << 4);
        offB[m] = rowB * 64 + ((l16 ^ ((rowB >> 1) & 3)) << 4);
    }

    f32x4 acc[4][4];
    #pragma unroll
    for (int i = 0; i < 4; ++i)
        #pragma unroll
        for (int j = 0; j < 4; ++j) acc[i][j] = (f32x4)0.0f;

    ushort8 ur[3][2];

    auto gldsA = [&](int kc, int buf) {
        char* dst = smem + buf * 8192;
        #pragma unroll
        for (int i = 0; i < 2; ++i)
            gl_lds16(Ag + srcOffA[i] + kc * 64, dst + dstOffA[i]);
    };
    auto loadU = [&](int slot, int kc) {
        #pragma unroll
        for (int q = 0; q < 2; ++q)
            ur[slot][q] = *reinterpret_cast<const ushort8*>(mrow + kc * 64 + q * 16);
    };
    // procB: affine+leaky on ur[slot] (chunk kc), pack bf16, swizzled ds_write to btbuf
    auto procB = [&](int slot, int kc, int btoff) {
        #pragma unroll
        for (int q = 0; q < 2; ++q) {
            const int kbase = kc * 32 + h * 16 + q * 8;
            float v[8];
            #pragma unroll
            for (int e = 0; e < 8; ++e)
                v[e] = leaky_f(fmaf(bf2f(ur[slot][q][e]), alf[kbase + e], bet[kbase + e]));
            uint4 pk;
            pk.x = pk2bf(v[0], v[1]);
            pk.y = pk2bf(v[2], v[3]);
            pk.z = pk2bf(v[4], v[5]);
            pk.w = pk2bf(v[6], v[7]);
            *reinterpret_cast<uint4*>(smem + btoff + bbase + ((((h << 1) + q) ^ bswz) << 4)) = pk;
        }
    };

    // prologue (FIFO order): u0; gldsA0; u1; gldsA1; u2. lgkm-only barrier (alf/bet
    // visibility, vmem stays in flight); procB(0) auto-waits u0; counted vmcnt wait.
    {
        const float* amt = am + t * NC;
        const float* bmt = bm + t * NC;
        const float2 a2 = *reinterpret_cast<const float2*>(amt + tid * 2);
        const float2 b2 = *reinterpret_cast<const float2*>(bmt + tid * 2);
        *reinterpret_cast<float2*>(alf + tid * 2) = a2;
        *reinterpret_cast<float2*>(bet + tid * 2) = b2;
    }
    loadU(0, 0);
    gldsA(0, 0);
    loadU(1, 1);
    gldsA(1, 1);
    loadU(2, 2);
    SB(); WAITL(); SB(); BAR();          // alf/bet visible to all waves; vmcnt untouched
    procB(0, 0, 24576);                  // auto-waits u0 only (oldest)
    SB(); WAITV6(); SB(); BAR();         // gldsA(0) done; u1,gldsA1,u2 stay in flight

    #pragma unroll
    for (int kc = 0; kc < 16; ++kc) {
        const int acur = (kc % 3) * 8192;
        const int bcur = 24576 + (kc & 1) * 8192;
        if (kc < 14) gldsA(kc + 2, (kc + 2) % 3);
        SB();
        if (kc < 15) procB((kc + 1) % 3, kc + 1, 24576 + ((kc + 1) & 1) * 8192);
        if (kc < 13) loadU(kc % 3, kc + 3);          // (kc+3)%3 == kc%3
        SB();
        {
            bf16x8 a[4], b[4];
            #pragma unroll
            for (int m = 0; m < 4; ++m) a[m] = *reinterpret_cast<const bf16x8*>(smem + acur + offA[m]);
            #pragma unroll
            for (int n = 0; n < 4; ++n) b[n] = *reinterpret_cast<const bf16x8*>(smem + bcur + offB[n]);
            PRIO1();
            #pragma unroll
            for (int m = 0; m < 4; ++m)
                #pragma unroll
                for (int n = 0; n < 4; ++n)
                    acc[m][n] = __builtin_amdgcn_mfma_f32_16x16x32_bf16(a[m], b[n], acc[m][n], 0, 0, 0);
            PRIO0();
        }
        SB();
        if (kc < 13)       { WAITV6(); }
        else if (kc == 13) { WAITV4(); }
        else if (kc == 14) { WAITV0(); }
        else               { WAITL();  }
        SB();
        BAR();
    }

    // epilogue: +sp, stats, ep transpose (granule XOR), coalesced store
    char* ep = smem;
    #pragma unroll
    for (int m = 0; m < 4; ++m) {
        const int oc = o0 + wo * 64 + m * 16 + (l16 << 2);
        float s1[4] = {0,0,0,0}, s2[4] = {0,0,0,0};
        #pragma unroll
        for (int nn = 0; nn < 4; ++nn) {
            const int b = (n0 >> 4) + wn * 4 + nn;
            const float4 sp4 = *reinterpret_cast<const float4*>(sp_bt + (size_t)b * NO + oc);
            const float spv[4] = {sp4.x, sp4.y, sp4.z, sp4.w};
            float pv[4];
            #pragma unroll
            for (int r = 0; r < 4; ++r) {
                const float v = acc[m][nn][r] + spv[r];
                pv[r] = v;
                s1[r] += v; s2[r] = fmaf(v, v, s2[r]);
            }
            uint2 uu;
            uu.x = pk2bf(pv[0], pv[1]);
            uu.y = pk2bf(pv[2], pv[3]);
            const int row = wn * 64 + nn * 16 + l15;
            const int g   = wo * 8 + m * 2 + (l16 >> 1);
            const int off = row * 256 + ((g ^ (row & 7)) << 4) + ((l16 & 1) << 3);
            *reinterpret_cast<uint2*>(ep + off) = uu;
        }
        #pragma unroll
        for (int r = 0; r < 4; ++r) {
            #pragma unroll
            for (int msk = 1; msk < 16; msk <<= 1) {
                s1[r] += __shfl_xor(s1[r], msk, 64);
                s2[r] += __shfl_xor(s2[r], msk, 64);
            }
            if (l15 == 0) {
                atomicAdd(&ssum[t * NO + oc + r], s1[r]);
                atomicAdd(&ssq[t * NO + oc + r], s2[r]);
            }
        }
    }
    SB(); WAITL(); SB(); BAR();
    #pragma unroll
    for (int p = 0; p < 8; ++p) {
        const int row = (p << 4) + (tid >> 4);
        const int c   = tid & 15;
        const uint4 v = *reinterpret_cast<const uint4*>(ep + row * 256 + ((c ^ (row & 7)) << 4));
        *reinterpret_cast<uint4*>((char*)praw + ((size_t)(t * 4096 + n0 + row)) * 1024
                                  + o0 * 2 + (c << 4)) = v;
    }
}

// ---------------- K7: out[t,b] = sigmoid(sum leaky(bn(praw)) * Wp2) ----------------------
// Lane owns a fixed o-slice (o8..o8+7); hw varies per e. ap/bp loads hoisted out of loop.
__global__ __launch_bounds__(256)
void k7_out(const unsigned short* __restrict__ praw, const float* __restrict__ ap,
            const float* __restrict__ bp, const float* __restrict__ wp2t,
            float* __restrict__ out)
{
    const int bx = blockIdx.x;
    const int t = bx >> 8, b = bx & 255;
    const int tid = threadIdx.x;
    const int o8 = (tid & 63) * 8;
    const int hwq = tid >> 6;            // wave id 0..3
    const unsigned short* pr = praw + ((size_t)(t * 256 + b)) * 8192;  // [hw][o]

    float av[8], bv[8];
    *reinterpret_cast<float4*>(av)     = *reinterpret_cast<const float4*>(ap + t * NO + o8);
    *reinterpret_cast<float4*>(av + 4) = *reinterpret_cast<const float4*>(ap + t * NO + o8 + 4);
    *reinterpret_cast<float4*>(bv)     = *reinterpret_cast<const float4*>(bp + t * NO + o8);
    *reinterpret_cast<float4*>(bv + 4) = *reinterpret_cast<const float4*>(bp + t * NO + o8 + 4);

    float acc = 0.0f;
    #pragma unroll
    for (int e = 0; e < 4; ++e) {
        const int hw = hwq + e * 4;
        const ushort8 u = *reinterpret_cast<const ushort8*>(pr + hw * 512 + o8);
        float wv[8];
        *reinterpret_cast<float4*>(wv)     = *reinterpret_cast<const float4*>(wp2t + hw * NO + o8);
        *reinterpret_cast<float4*>(wv + 4) = *reinterpret_cast<const float4*>(wp2t + hw * NO + o8 + 4);
        #pragma unroll
        for (int j = 0; j < 8; ++j) {
            const float x = leaky_f(fmaf(bf2f(u[j]), av[j], bv[j]));
            acc = fmaf(x, wv[j], acc);
        }
    }
    #pragma unroll
    for (int m = 1; m < 64; m <<= 1) acc += __shfl_xor(acc, m, 64);
    __shared__ float red[4];
    if ((tid & 63) == 0) red[tid >> 6] = acc;
    __syncthreads();
    if (tid == 0) {
        float z = red[0] + red[1] + red[2] + red[3];
        out[t * NB + b] = 1.0f / (1.0f + __expf(-z));
    }
}

// ------------------------------------------------------------------------------------------
extern "C" void kernel_launch(void* const* d_in, const int* in_sizes, int n_in,
                              void* d_out, int out_size, void* d_ws, size_t ws_size,
                              hipStream_t stream)
{
    const float* frames = (const float*)d_in[0];
    const float* sent   = (const float*)d_in[1];
    const float* W_lin  = (const float*)d_in[2];
    const float* b_lin  = (const float*)d_in[3];
    const float* g_bn_s = (const float*)d_in[4];
    const float* b_bn_s = (const float*)d_in[5];
    const float* W_mm   = (const float*)d_in[6];
    const float* g_bn_m = (const float*)d_in[7];
    const float* b_bn_m = (const float*)d_in[8];
    const float* W_p1   = (const float*)d_in[9];
    const float* g_bn_p = (const float*)d_in[10];
    const float* b_bn_p = (const float*)d_in[11];
    const float* W_p2   = (const float*)d_in[12];
    float* out = (float*)d_out;

    char* ws = (char*)d_ws;
    const size_t BIG = 134217728;                    // 32*256*16*512*2
    unsigned short* bufA = (unsigned short*)ws;      // mdT, later praw (aliased)
    unsigned short* bufB = (unsigned short*)(ws + BIG);  // mraw
    char* small = ws + 2 * BIG;
    float* msum = (float*)(small);                   // 16384 f32 each
    float* msq  = (float*)(small + 65536);
    float* psum = (float*)(small + 131072);
    float* psq  = (float*)(small + 196608);
    float* am   = (float*)(small + 262144);
    float* bm   = (float*)(small + 327680);
    float* apv  = (float*)(small + 393216);
    float* bpv  = (float*)(small + 458752);
    float* s_t  = (float*)(small + 524288);          // 256*256 f32
    float* sp_bt= (float*)(small + 786432);          // 256*512 f32
    float* wp2t = (float*)(small + 1310720);         // 16*512 f32
    unsigned short* WmmBf = (unsigned short*)(small + 1343488);  // 512*512 bf16
    unsigned short* Wp1Bf = (unsigned short*)(small + 1867776);  // 512*512 bf16

    hipMemsetAsync(small, 0, 262144, stream);
    kprep_w<<<1056, 256, 0, stream>>>(W_mm, W_p1, W_p2, WmmBf, Wp1Bf, wp2t);
    kprep_diff<<<1024, 256, 0, stream>>>(frames, bufA);
    k1_sent<<<256, 256, 0, stream>>>(sent, W_lin, b_lin, g_bn_s, b_bn_s, s_t);
    k2_sp<<<512, 256, 0, stream>>>(s_t, W_p1, sp_bt);
    k3_mfma<<<4096, 256, 0, stream>>>(WmmBf, bufA, bufB, msum, msq);
    kstats<<<64, 256, 0, stream>>>(msum, msq, g_bn_m, b_bn_m, am, bm);
    k5_mfma<<<4096, 256, 0, stream>>>(Wp1Bf, bufB, am, bm, sp_bt, bufA, psum, psq);
    kstats<<<64, 256, 0, stream>>>(psum, psq, g_bn_p, b_bn_p, apv, bpv);
    k7_out<<<8192, 256, 0, stream>>>(bufA, apv, bpv, wp2t, out);
}